// Round 8
// baseline (1076.584 us; speedup 1.0000x reference)
//
#include <hip/hip_runtime.h>

#define D   42
#define ED  10
#define NU  16384
#define EU  32768
#define NV  20480
#define EV  40960
#define NT  (NU + NV)   // 36864
#define ET  (EU + EV)   // 73728
#define GJ  462         // 11 * 42 (10 h-channels + bias channel)
#define GP  464         // padded g/A row stride (116 float4)
#define STEPS 6

typedef float floatx4 __attribute__((ext_vector_type(4)));

// ---------------- prep: A[phase][i][k*42+o] = en2_w[k, i*42+o] (k<10) | en2_b (k=10) --------
__global__ void k_prep(const float* __restrict__ su_w2, const float* __restrict__ su_b2,
                       const float* __restrict__ sv_w2, const float* __restrict__ sv_b2,
                       float* __restrict__ A, float* __restrict__ mean) {
    int gid = blockIdx.x * 256 + threadIdx.x;
    if (gid < 128) mean[gid] = 0.f;
    if (gid >= 2 * D * GP) return;
    int phase = gid / (D * GP);
    int r = gid - phase * D * GP;
    int i = r / GP, j = r - i * GP;
    const float* w2 = phase ? sv_w2 : su_w2;
    const float* b2 = phase ? sv_b2 : su_b2;
    float v = 0.f;
    if (j < GJ) {
        int k = j / D, o = j - k * D;
        v = (k < ED) ? w2[k * (D * D) + i * D + o] : b2[i * D + o];
    }
    A[gid] = v;
}

// ---------------- lin0: out = relu(x @ lw + lb) --------------------------------------------
__global__ void k_lin0(const float* __restrict__ su_x, const float* __restrict__ sv_x,
                       const float* __restrict__ su_w, const float* __restrict__ su_b,
                       const float* __restrict__ sv_w, const float* __restrict__ sv_b,
                       float* __restrict__ out) {
    int gid = blockIdx.x * 256 + threadIdx.x;
    if (gid >= NT * D) return;
    int n = gid / D, o = gid - n * D;
    const float *x, *w, *b; int nl;
    if (n < NU) { x = su_x; w = su_w; b = su_b; nl = n; }
    else        { x = sv_x; w = sv_w; b = sv_b; nl = n - NU; }
    float s = b[o];
    #pragma unroll
    for (int i = 0; i < D; i++) s += x[nl * D + i] * w[i * D + o];
    out[gid] = fmaxf(s, 0.f);
}

// ---------------- CSR build --------------------------------------------------------------
__global__ void k_zcnt(int* __restrict__ p, int n) {
    int gid = blockIdx.x * 256 + threadIdx.x;
    if (gid < n) p[gid] = 0;
}

__global__ void k_count(const int* __restrict__ su_src, const int* __restrict__ su_dst,
                        const int* __restrict__ sv_src, const int* __restrict__ sv_dst,
                        int* __restrict__ outDeg, int* __restrict__ inDeg) {
    int e = blockIdx.x * 256 + threadIdx.x;
    if (e >= ET) return;
    int src, dst;
    if (e < EU) { src = su_src[e];           dst = su_dst[e]; }
    else        { src = sv_src[e - EU] + NU; dst = sv_dst[e - EU] + NU; }
    atomicAdd(&outDeg[src], 1);
    atomicAdd(&inDeg[dst], 1);
}

// exclusive prefix sums for both deg arrays; 1024 threads x 36 elements = 36864 = NT
__global__ __launch_bounds__(1024) void k_scan(const int* __restrict__ degO, int* __restrict__ offO,
                                               const int* __restrict__ degI, int* __restrict__ offI) {
    __shared__ int part[1024];
    int t = threadIdx.x;
    for (int a = 0; a < 2; a++) {
        const int* deg = a ? degI : degO;
        int* off = a ? offI : offO;
        int loc[36];
        int base = t * 36;
        int s = 0;
        #pragma unroll
        for (int j = 0; j < 36; j++) { loc[j] = s; s += deg[base + j]; }
        part[t] = s;
        __syncthreads();
        for (int d = 1; d < 1024; d <<= 1) {
            int v = (t >= d) ? part[t - d] : 0;
            __syncthreads();
            part[t] += v;
            __syncthreads();
        }
        int excl = part[t] - s;
        #pragma unroll
        for (int j = 0; j < 36; j++) off[base + j] = excl + loc[j];
        if (t == 1023) off[NT] = excl + s;
        __syncthreads();
    }
}

__global__ void k_place(const int* __restrict__ su_src, const int* __restrict__ su_dst,
                        const int* __restrict__ sv_src, const int* __restrict__ sv_dst,
                        const int* __restrict__ offO, int* __restrict__ cntO,
                        const int* __restrict__ offI, int* __restrict__ cntI,
                        int* __restrict__ inList, int* __restrict__ srcSorted,
                        int* __restrict__ pOf) {
    int e = blockIdx.x * 256 + threadIdx.x;
    if (e >= ET) return;
    int src, dst;
    if (e < EU) { src = su_src[e];           dst = su_dst[e]; }
    else        { src = sv_src[e - EU] + NU; dst = sv_dst[e - EU] + NU; }
    int p = offO[src] + atomicAdd(&cntO[src], 1);
    int q = offI[dst] + atomicAdd(&cntI[dst], 1);
    inList[q] = p;
    srcSorted[p] = src;
    pOf[e] = p;
}

// ---------------- edge h: h_sorted[p] = [relu(ef@en1_w+en1_b), 1, 0] ------------------------
__global__ void k_edgeh(const float* __restrict__ su_e, const float* __restrict__ sv_e,
                        const float* __restrict__ su_w1, const float* __restrict__ su_b1,
                        const float* __restrict__ sv_w1, const float* __restrict__ sv_b1,
                        const int* __restrict__ pOf, float* __restrict__ hs) {
    __shared__ float w1s[2][ED * ED];
    __shared__ float b1s[2][ED];
    int tid = threadIdx.x;
    if (tid < ED * ED) { w1s[0][tid] = su_w1[tid]; w1s[1][tid] = sv_w1[tid]; }
    if (tid < ED)      { b1s[0][tid] = su_b1[tid]; b1s[1][tid] = sv_b1[tid]; }
    __syncthreads();
    int e = blockIdx.x * 256 + tid;
    if (e >= ET) return;
    int ph = (e >= EU);
    const float* ef = ph ? (sv_e + (size_t)(e - EU) * ED) : (su_e + (size_t)e * ED);
    float v[ED];
    #pragma unroll
    for (int j = 0; j < ED; j++) v[j] = ef[j];
    size_t p = (size_t)pOf[e] * 12;
    #pragma unroll
    for (int k = 0; k < ED; k++) {
        float s = b1s[ph][k];
        #pragma unroll
        for (int j = 0; j < ED; j++) s += v[j] * w1s[ph][j * ED + k];
        hs[p + k] = fmaxf(s, 0.f);
    }
    hs[p + 10] = 1.f;
    hs[p + 11] = 0.f;
}

// ---------------- fused register-tiled g GEMM (in LDS) + per-edge msg -----------------------
// 32 nodes/block, 512 threads. GEMM: thread = 4 rows x 8 cols, A streamed from L2 (broadcast),
// outT in LDS -> 3 mem ops per 32 FMA4. g tile stays in LDS; msg phase contracts with h.
__global__ __launch_bounds__(512, 2) void k_gmsg2(const float* __restrict__ out,
                                                  const float* __restrict__ A,
                                                  const int* __restrict__ offO,
                                                  const int* __restrict__ srcSorted,
                                                  const float* __restrict__ hs,
                                                  float* __restrict__ msg) {
    __shared__ float outT[D * 36];      // transposed out tile: outT[i][nn], stride 36 (6,048 B)
    __shared__ float g_lds[32 * GP];    // 59,392 B   (total 65,440 B -> 2 blocks/CU)
    int tid = threadIdx.x;
    int n0 = blockIdx.x * 32;
    const floatx4* A4 = (const floatx4*)(A + (n0 >= NU ? D * GP : 0));

    // load out tile transposed (conflict-free LDS writes: lanes span nn)
    for (int idx = tid; idx < 32 * D; idx += 512) {
        int nn = idx & 31, i = idx >> 5;
        outT[i * 36 + nn] = out[(size_t)(n0 + nn) * D + i];
    }
    __syncthreads();

    // GEMM: 464 workers: rg = row-group (4 rows), cg = col-group (8 cols = 2 float4)
    if (tid < 464) {
        int cg = tid % 58, rg = tid / 58;
        const floatx4* oT4 = (const floatx4*)outT;
        floatx4 acc[4][2];
        #pragma unroll
        for (int r = 0; r < 4; r++) { acc[r][0] = (floatx4)(0.f); acc[r][1] = (floatx4)(0.f); }
        for (int k = 0; k < D; k++) {
            floatx4 a0 = A4[k * 116 + 2 * cg];
            floatx4 a1 = A4[k * 116 + 2 * cg + 1];
            floatx4 o4 = oT4[k * 9 + rg];        // rows 4rg..4rg+3 at feature k
            #pragma unroll
            for (int r = 0; r < 4; r++) {
                acc[r][0] += a0 * o4[r];
                acc[r][1] += a1 * o4[r];
            }
        }
        floatx4* gl4 = (floatx4*)g_lds;
        #pragma unroll
        for (int r = 0; r < 4; r++) {
            gl4[(4 * rg + r) * 116 + 2 * cg]     = acc[r][0];
            gl4[(4 * rg + r) * 116 + 2 * cg + 1] = acc[r][1];
        }
    }
    __syncthreads();

    // msg: out-edges of these 32 nodes are contiguous [p0,p1) in src-sorted CSR
    int p0 = offO[n0], p1 = offO[n0 + 32];
    int nwork = (p1 - p0) * D;
    for (int idx = tid; idx < nwork; idx += 512) {
        int pr = idx / D, o = idx - pr * D;
        int p = p0 + pr;
        int local = srcSorted[p] - n0;
        const float* hrow = hs + (size_t)p * 12;
        const float* grow = g_lds + local * GP;
        float s = 0.f;
        #pragma unroll
        for (int k = 0; k <= ED; k++) s += hrow[k] * grow[k * D + o];
        msg[(size_t)p * D + o] = s;
    }
}

// ---------------- gather msg by dst + residual + relu + register-tiled GEMM -----------------
// 32 nodes/block, 128 threads. m stored TRANSPOSED in LDS; GEMM thread = 4 rows x 4 cols.
__global__ __launch_bounds__(128) void k_upd2(const int* __restrict__ offI,
                                              const int* __restrict__ inList,
                                              const float* __restrict__ msg,
                                              float* __restrict__ out,
                                              const float* __restrict__ su_mw, const float* __restrict__ su_mb,
                                              const float* __restrict__ su_cb,
                                              const float* __restrict__ sv_mw, const float* __restrict__ sv_mb,
                                              const float* __restrict__ sv_cb) {
    __shared__ float mT[D * 36];        // transposed m: mT[i][nn]  (6,048 B)
    __shared__ float mw_lds[D * 48];    // padded weights          (8,064 B)
    int tid = threadIdx.x;
    int n0 = blockIdx.x * 32;
    int ph = (n0 >= NU);
    const float* mw = ph ? sv_mw : su_mw;
    const float* mb = ph ? sv_mb : su_mb;
    const float* cb = ph ? sv_cb : su_cb;
    for (int idx = tid; idx < D * 48; idx += 128) {
        int i = idx / 48, o = idx - i * 48;
        mw_lds[idx] = (o < D) ? mw[i * D + o] : 0.f;
    }
    // gather + residual + relu -> mT (lanes span nn: conflict-free writes)
    for (int idx = tid; idx < 32 * D; idx += 128) {
        int nn = idx & 31, o = idx >> 5;
        int n = n0 + nn;
        int q0 = offI[n], q1 = offI[n + 1];
        float s = out[(size_t)n * D + o] + cb[o];
        for (int q = q0; q < q1; q++) s += msg[(size_t)inList[q] * D + o];
        mT[o * 36 + nn] = fmaxf(s, 0.f);
    }
    __syncthreads();
    // GEMM: 88 workers: rg 0..7 (4 rows), cg 0..10 (4 cols)
    if (tid < 88) {
        int cg = tid % 11, rg = tid / 11;
        const floatx4* mT4 = (const floatx4*)mT;
        const floatx4* mw4 = (const floatx4*)mw_lds;
        floatx4 acc[4];
        #pragma unroll
        for (int r = 0; r < 4; r++) acc[r] = (floatx4)(0.f);
        for (int k = 0; k < D; k++) {
            floatx4 a = mT4[k * 9 + rg];         // rows 4rg..4rg+3
            floatx4 w = mw4[k * 12 + cg];        // cols 4cg..4cg+3
            #pragma unroll
            for (int r = 0; r < 4; r++) acc[r] += w * a[r];
        }
        #pragma unroll
        for (int r = 0; r < 4; r++) {
            size_t row = (size_t)(n0 + 4 * rg + r) * D;
            #pragma unroll
            for (int c = 0; c < 4; c++) {
                int col = 4 * cg + c;
                if (col < D) out[row + col] = fmaxf(acc[r][c] + mb[col], 0.f);
            }
        }
    }
}

// ---------------- reduce: mean[ph*42+o] += sum_n (out[n,o] + x[n,o]) ------------------------
__global__ void k_reduce(const float* __restrict__ out, const float* __restrict__ su_x,
                         const float* __restrict__ sv_x, float* __restrict__ mean) {
    __shared__ float sdata[6 * D];
    int tid = threadIdx.x;
    int bid = blockIdx.x;
    int n0, ph, nl0;
    const float* x;
    if (bid < NU / 128) { ph = 0; n0 = bid * 128;                 nl0 = n0;      x = su_x; }
    else                { ph = 1; n0 = NU + (bid - NU/128) * 128; nl0 = n0 - NU; x = sv_x; }
    if (tid < 6 * D) {
        int o = tid % D, r = tid / D;
        float acc = 0.f;
        for (int nn = r; nn < 128; nn += 6)
            acc += out[(size_t)(n0 + nn) * D + o] + x[(size_t)(nl0 + nn) * D + o];
        sdata[r * D + o] = acc;
    }
    __syncthreads();
    if (tid < D) {
        float tot = 0.f;
        #pragma unroll
        for (int r = 0; r < 6; r++) tot += sdata[r * D + tid];
        atomicAdd(&mean[ph * D + tid], tot);
    }
}

// ---------------- final MLP --------------------------------------------------------------
__global__ void k_mlp(const float* __restrict__ mean,
                      const float* __restrict__ fc1w, const float* __restrict__ fc1b,
                      const float* __restrict__ fc2w, const float* __restrict__ fc2b,
                      const float* __restrict__ fc3w, const float* __restrict__ fc3b,
                      float* __restrict__ outp) {
    __shared__ float c[4 * D];
    __shared__ float h1[256];
    __shared__ float h2[128];
    int t = threadIdx.x;
    if (t < 4 * D) {
        float v;
        if (t < 2 * D) v = mean[t < D ? t : t - D] * (1.f / NU);
        else { int q = t - 2 * D; v = mean[D + (q < D ? q : q - D)] * (1.f / NV); }
        c[t] = v;
    }
    __syncthreads();
    float s = fc1b[t];
    for (int j = 0; j < 4 * D; j++) s += c[j] * fc1w[j * 256 + t];
    h1[t] = fmaxf(s, 0.f);
    __syncthreads();
    if (t < 128) {
        float s2 = fc2b[t];
        for (int j = 0; j < 256; j++) s2 += h1[j] * fc2w[j * 128 + t];
        h2[t] = fmaxf(s2, 0.f);
    }
    __syncthreads();
    if (t == 0) {
        float s3 = fc3b[0];
        for (int j = 0; j < 128; j++) s3 += h2[j] * fc3w[j];
        outp[0] = s3;
    }
}

extern "C" void kernel_launch(void* const* d_in, const int* in_sizes, int n_in,
                              void* d_out, int out_size, void* d_ws, size_t ws_size,
                              hipStream_t stream) {
    const float* su_x     = (const float*)d_in[0];
    const float* su_e     = (const float*)d_in[1];
    const int*   su_src   = (const int*)d_in[2];
    const int*   su_dst   = (const int*)d_in[3];
    const float* sv_x     = (const float*)d_in[4];
    const float* sv_e     = (const float*)d_in[5];
    const int*   sv_src   = (const int*)d_in[6];
    const int*   sv_dst   = (const int*)d_in[7];
    const float* su_lin0w = (const float*)d_in[8];
    const float* su_lin0b = (const float*)d_in[9];
    const float* su_msgw  = (const float*)d_in[10];
    const float* su_msgb  = (const float*)d_in[11];
    const float* su_en1w  = (const float*)d_in[12];
    const float* su_en1b  = (const float*)d_in[13];
    const float* su_en2w  = (const float*)d_in[14];
    const float* su_en2b  = (const float*)d_in[15];
    const float* su_convb = (const float*)d_in[16];
    const float* sv_lin0w = (const float*)d_in[17];
    const float* sv_lin0b = (const float*)d_in[18];
    const float* sv_msgw  = (const float*)d_in[19];
    const float* sv_msgb  = (const float*)d_in[20];
    const float* sv_en1w  = (const float*)d_in[21];
    const float* sv_en1b  = (const float*)d_in[22];
    const float* sv_en2w  = (const float*)d_in[23];
    const float* sv_en2b  = (const float*)d_in[24];
    const float* sv_convb = (const float*)d_in[25];
    const float* fc1w     = (const float*)d_in[26];
    const float* fc1b     = (const float*)d_in[27];
    const float* fc2w     = (const float*)d_in[28];
    const float* fc2b     = (const float*)d_in[29];
    const float* fc3w     = (const float*)d_in[30];
    const float* fc3b     = (const float*)d_in[31];

    float* ws   = (float*)d_ws;
    float* out  = ws;                            // NT*D
    float* msg  = out  + (size_t)NT * D;         // ET*D
    float* hs   = msg  + (size_t)ET * D;         // ET*12
    float* A    = hs   + (size_t)ET * 12;        // 2*D*GP
    float* mean = A    + (size_t)2 * D * GP;     // 128
    int* ib     = (int*)(mean + 128);
    int* outDeg = ib;                            // NT
    int* inDeg  = outDeg + NT;                   // NT
    int* outCnt = inDeg  + NT;                   // NT
    int* inCnt  = outCnt + NT;                   // NT   (4*NT zeroed together)
    int* outOff = inCnt  + NT;                   // NT+1
    int* inOff  = outOff + (NT + 1);             // NT+1
    int* inList = inOff  + (NT + 1);             // ET
    int* srcS   = inList + ET;                   // ET
    int* pOf    = srcS   + ET;                   // ET
    // total ws use ~24 MB

    // zero pred slot + the 16384x20480 interaction output (rocclr fill ~6.4 TB/s, capture-safe)
    hipMemsetAsync(d_out, 0, (size_t)out_size * sizeof(float), stream);

    k_prep<<<(2 * D * GP + 255) / 256, 256, 0, stream>>>(su_en2w, su_en2b, sv_en2w, sv_en2b, A, mean);
    k_lin0<<<(NT * D + 255) / 256, 256, 0, stream>>>(su_x, sv_x, su_lin0w, su_lin0b, sv_lin0w, sv_lin0b, out);

    // CSR build (per call; deterministic sets, order within a node may vary -> fp jitter << tol)
    k_zcnt<<<(4 * NT + 255) / 256, 256, 0, stream>>>(outDeg, 4 * NT);
    k_count<<<(ET + 255) / 256, 256, 0, stream>>>(su_src, su_dst, sv_src, sv_dst, outDeg, inDeg);
    k_scan<<<1, 1024, 0, stream>>>(outDeg, outOff, inDeg, inOff);
    k_place<<<(ET + 255) / 256, 256, 0, stream>>>(su_src, su_dst, sv_src, sv_dst,
                                                  outOff, outCnt, inOff, inCnt, inList, srcS, pOf);
    k_edgeh<<<(ET + 255) / 256, 256, 0, stream>>>(su_e, sv_e, su_en1w, su_en1b, sv_en1w, sv_en1b, pOf, hs);

    for (int s = 0; s < STEPS; s++) {
        k_gmsg2<<<NT / 32, 512, 0, stream>>>(out, A, outOff, srcS, hs, msg);
        k_upd2<<<NT / 32, 128, 0, stream>>>(inOff, inList, msg, out,
                                            su_msgw, su_msgb, su_convb, sv_msgw, sv_msgb, sv_convb);
    }

    k_reduce<<<NU / 128 + NV / 128, 256, 0, stream>>>(out, su_x, sv_x, mean);
    k_mlp<<<1, 256, 0, stream>>>(mean, fc1w, fc1b, fc2w, fc2b, fc3w, fc3b, (float*)d_out);
}

// Round 9
// 846.909 us; speedup vs baseline: 1.2712x; 1.2712x over previous
//
#include <hip/hip_runtime.h>

#define D   42
#define ED  10
#define NU  16384
#define EU  32768
#define NV  20480
#define EV  40960
#define NT  (NU + NV)   // 36864
#define ET  (EU + EV)   // 73728
#define GJ  462         // 11 * 42 (10 h-channels + bias channel)
#define GP  464         // padded g/A row stride (116 float4)
#define STEPS 6

typedef float floatx4 __attribute__((ext_vector_type(4)));

// ---------------- prep: A[phase][i][k*42+o] = en2_w[k, i*42+o] (k<10) | en2_b (k=10) --------
__global__ void k_prep(const float* __restrict__ su_w2, const float* __restrict__ su_b2,
                       const float* __restrict__ sv_w2, const float* __restrict__ sv_b2,
                       float* __restrict__ A, float* __restrict__ mean) {
    int gid = blockIdx.x * 256 + threadIdx.x;
    if (gid < 128) mean[gid] = 0.f;
    if (gid >= 2 * D * GP) return;
    int phase = gid / (D * GP);
    int r = gid - phase * D * GP;
    int i = r / GP, j = r - i * GP;
    const float* w2 = phase ? sv_w2 : su_w2;
    const float* b2 = phase ? sv_b2 : su_b2;
    float v = 0.f;
    if (j < GJ) {
        int k = j / D, o = j - k * D;
        v = (k < ED) ? w2[k * (D * D) + i * D + o] : b2[i * D + o];
    }
    A[gid] = v;
}

// ---------------- CSR build --------------------------------------------------------------
__global__ void k_zcnt(int* __restrict__ p, int n) {
    int gid = blockIdx.x * 256 + threadIdx.x;
    if (gid < n) p[gid] = 0;
}

__global__ void k_count(const int* __restrict__ su_src, const int* __restrict__ su_dst,
                        const int* __restrict__ sv_src, const int* __restrict__ sv_dst,
                        int* __restrict__ outDeg, int* __restrict__ inDeg) {
    int e = blockIdx.x * 256 + threadIdx.x;
    if (e >= ET) return;
    int src, dst;
    if (e < EU) { src = su_src[e];           dst = su_dst[e]; }
    else        { src = sv_src[e - EU] + NU; dst = sv_dst[e - EU] + NU; }
    atomicAdd(&outDeg[src], 1);
    atomicAdd(&inDeg[dst], 1);
}

__global__ __launch_bounds__(1024) void k_scan(const int* __restrict__ degO, int* __restrict__ offO,
                                               const int* __restrict__ degI, int* __restrict__ offI) {
    __shared__ int part[1024];
    int t = threadIdx.x;
    for (int a = 0; a < 2; a++) {
        const int* deg = a ? degI : degO;
        int* off = a ? offI : offO;
        int loc[36];
        int base = t * 36;
        int s = 0;
        #pragma unroll
        for (int j = 0; j < 36; j++) { loc[j] = s; s += deg[base + j]; }
        part[t] = s;
        __syncthreads();
        for (int d = 1; d < 1024; d <<= 1) {
            int v = (t >= d) ? part[t - d] : 0;
            __syncthreads();
            part[t] += v;
            __syncthreads();
        }
        int excl = part[t] - s;
        #pragma unroll
        for (int j = 0; j < 36; j++) off[base + j] = excl + loc[j];
        if (t == 1023) off[NT] = excl + s;
        __syncthreads();
    }
}

__global__ void k_place(const int* __restrict__ su_src, const int* __restrict__ su_dst,
                        const int* __restrict__ sv_src, const int* __restrict__ sv_dst,
                        const int* __restrict__ offO, int* __restrict__ cntO,
                        const int* __restrict__ offI, int* __restrict__ cntI,
                        int* __restrict__ inList, int* __restrict__ srcSorted,
                        int* __restrict__ pOf) {
    int e = blockIdx.x * 256 + threadIdx.x;
    if (e >= ET) return;
    int src, dst;
    if (e < EU) { src = su_src[e];           dst = su_dst[e]; }
    else        { src = sv_src[e - EU] + NU; dst = sv_dst[e - EU] + NU; }
    int p = offO[src] + atomicAdd(&cntO[src], 1);
    int q = offI[dst] + atomicAdd(&cntI[dst], 1);
    inList[q] = p;
    srcSorted[p] = src;
    pOf[e] = p;
}

// ---------------- edge h: h_sorted[p] = [relu(ef@en1_w+en1_b), 1, 0] ------------------------
__global__ void k_edgeh(const float* __restrict__ su_e, const float* __restrict__ sv_e,
                        const float* __restrict__ su_w1, const float* __restrict__ su_b1,
                        const float* __restrict__ sv_w1, const float* __restrict__ sv_b1,
                        const int* __restrict__ pOf, float* __restrict__ hs) {
    __shared__ float w1s[2][ED * ED];
    __shared__ float b1s[2][ED];
    int tid = threadIdx.x;
    if (tid < ED * ED) { w1s[0][tid] = su_w1[tid]; w1s[1][tid] = sv_w1[tid]; }
    if (tid < ED)      { b1s[0][tid] = su_b1[tid]; b1s[1][tid] = sv_b1[tid]; }
    __syncthreads();
    int e = blockIdx.x * 256 + tid;
    if (e >= ET) return;
    int ph = (e >= EU);
    const float* ef = ph ? (sv_e + (size_t)(e - EU) * ED) : (su_e + (size_t)e * ED);
    float v[ED];
    #pragma unroll
    for (int j = 0; j < ED; j++) v[j] = ef[j];
    size_t p = (size_t)pOf[e] * 12;
    #pragma unroll
    for (int k = 0; k < ED; k++) {
        float s = b1s[ph][k];
        #pragma unroll
        for (int j = 0; j < ED; j++) s += v[j] * w1s[ph][j * ED + k];
        hs[p + k] = fmaxf(s, 0.f);
    }
    hs[p + 10] = 1.f;
    hs[p + 11] = 0.f;
}

// ---------------- fused step: [gather msg + node-GEMM]  ->  [g GEMM + edge msg] -------------
// 32 nodes/block, 512 threads, 157.5 KB LDS (1 block/CU).
// first=1: mT <- x (lin0 fused), W = lin0_w.  first=0: mT <- relu(out+cb+sum msgR), W = msg_w.
// Writes out (global, own nodes) then computes g in LDS and writes msgW for own out-edges.
__global__ __launch_bounds__(512, 1) void k_step(float* __restrict__ out,
                                                 const float* __restrict__ A,
                                                 const int* __restrict__ offO,
                                                 const int* __restrict__ srcSorted,
                                                 const float* __restrict__ hs,
                                                 float* __restrict__ msgW,
                                                 const float* __restrict__ msgR,
                                                 const int* __restrict__ offI,
                                                 const int* __restrict__ inList,
                                                 const float* __restrict__ su_x,
                                                 const float* __restrict__ sv_x,
                                                 const float* __restrict__ su_W, const float* __restrict__ su_b,
                                                 const float* __restrict__ sv_W, const float* __restrict__ sv_b,
                                                 const float* __restrict__ su_cb, const float* __restrict__ sv_cb,
                                                 int first) {
    __shared__ float A_lds[D * GP];     // 77,952 B
    __shared__ float g_lds[32 * GP];    // 59,392 B
    __shared__ float outT[D * 36];      //  6,048 B  (transposed: [i][nn])
    __shared__ float mT[D * 36];        //  6,048 B
    __shared__ float w_lds[D * 48];     //  8,064 B   total 157,504 B
    int tid = threadIdx.x;
    int n0 = blockIdx.x * 32;
    int ph = (n0 >= NU);

    // ---- stage A (issue first: latency hides under update phase) ----
    const floatx4* Ag = (const floatx4*)(A + (ph ? D * GP : 0));
    floatx4* Al4 = (floatx4*)A_lds;
    for (int idx = tid; idx < D * GP / 4; idx += 512) Al4[idx] = Ag[idx];

    // ---- stage W (+pad) ----
    const float* W = ph ? sv_W : su_W;
    const float* b = ph ? sv_b : su_b;
    for (int idx = tid; idx < D * 48; idx += 512) {
        int i = idx / 48, o = idx - i * 48;
        w_lds[idx] = (o < D) ? W[i * D + o] : 0.f;
    }

    // ---- build mT ----
    if (first) {
        const float* x = ph ? (sv_x + (size_t)(n0 - NU) * D) : (su_x + (size_t)n0 * D);
        for (int idx = tid; idx < 32 * D; idx += 512) {
            int i = idx % D, nn = idx / D;
            mT[i * 36 + nn] = x[(size_t)nn * D + i];
        }
    } else {
        const float* cb = ph ? sv_cb : su_cb;
        for (int idx = tid; idx < 32 * D; idx += 512) {
            int o = idx % D, nn = idx / D;
            int n = n0 + nn;
            int q0 = offI[n], q1 = offI[n + 1];
            float s = out[(size_t)n * D + o] + cb[o];
            for (int q = q0; q < q1; q++) s += msgR[(size_t)inList[q] * D + o];
            mT[o * 36 + nn] = fmaxf(s, 0.f);
        }
    }
    __syncthreads();

    // ---- node GEMM: v = relu(mT @ W + b) -> out(global) + outT(LDS) ----
    for (int idx = tid; idx < 32 * D; idx += 512) {
        int o = idx % D, nn = idx / D;
        float s = b[o];
        #pragma unroll
        for (int i = 0; i < D; i++) s += mT[i * 36 + nn] * w_lds[i * 48 + o];
        float v = fmaxf(s, 0.f);
        out[(size_t)(n0 + nn) * D + o] = v;
        outT[o * 36 + nn] = v;
    }
    __syncthreads();

    // ---- g GEMM: 232 workers, 8 cols x 8 nodes per thread ----
    if (tid < 232) {
        int cg = tid % 58, ng = tid / 58;   // cg: 2 float4 cols; ng: 8 nodes
        const floatx4* oT4 = (const floatx4*)outT;
        floatx4 acc[8][2];
        #pragma unroll
        for (int r = 0; r < 8; r++) { acc[r][0] = (floatx4)(0.f); acc[r][1] = (floatx4)(0.f); }
        for (int k = 0; k < D; k++) {
            floatx4 a0 = Al4[k * 116 + 2 * cg];
            floatx4 a1 = Al4[k * 116 + 2 * cg + 1];
            floatx4 o0 = oT4[k * 9 + 2 * ng];
            floatx4 o1 = oT4[k * 9 + 2 * ng + 1];
            #pragma unroll
            for (int r = 0; r < 4; r++) {
                acc[r][0]     += a0 * o0[r];
                acc[r][1]     += a1 * o0[r];
                acc[r + 4][0] += a0 * o1[r];
                acc[r + 4][1] += a1 * o1[r];
            }
        }
        floatx4* gl4 = (floatx4*)g_lds;
        #pragma unroll
        for (int r = 0; r < 8; r++) {
            gl4[(8 * ng + r) * 116 + 2 * cg]     = acc[r][0];
            gl4[(8 * ng + r) * 116 + 2 * cg + 1] = acc[r][1];
        }
    }
    __syncthreads();

    // ---- edge msg: out-edges contiguous [p0,p1) in src-sorted CSR ----
    int p0 = offO[n0], p1 = offO[n0 + 32];
    int nwork = (p1 - p0) * D;
    for (int idx = tid; idx < nwork; idx += 512) {
        int pr = idx / D, o = idx - pr * D;
        int p = p0 + pr;
        int local = srcSorted[p] - n0;
        const float* hrow = hs + (size_t)p * 12;
        const float* grow = g_lds + local * GP;
        float s = 0.f;
        #pragma unroll
        for (int k = 0; k <= ED; k++) s += hrow[k] * grow[k * D + o];
        msgW[(size_t)p * D + o] = s;
    }
}

// ---------------- final update (no g needed): high-occupancy version ------------------------
__global__ __launch_bounds__(256) void k_updF(const int* __restrict__ offI,
                                              const int* __restrict__ inList,
                                              const float* __restrict__ msg,
                                              float* __restrict__ out,
                                              const float* __restrict__ su_mw, const float* __restrict__ su_mb,
                                              const float* __restrict__ su_cb,
                                              const float* __restrict__ sv_mw, const float* __restrict__ sv_mb,
                                              const float* __restrict__ sv_cb) {
    __shared__ float mw_lds[D * D];
    __shared__ float mloc[32 * 44];
    int tid = threadIdx.x;
    int n0 = blockIdx.x * 32;
    int ph = (n0 >= NU);
    const float* mw = ph ? sv_mw : su_mw;
    const float* mb = ph ? sv_mb : su_mb;
    const float* cb = ph ? sv_cb : su_cb;
    for (int idx = tid; idx < D * D; idx += 256) mw_lds[idx] = mw[idx];
    for (int idx = tid; idx < 32 * D; idx += 256) {
        int o = idx % D, nn = idx / D;
        int n = n0 + nn;
        int q0 = offI[n], q1 = offI[n + 1];
        float s = out[(size_t)n * D + o] + cb[o];
        for (int q = q0; q < q1; q++) s += msg[(size_t)inList[q] * D + o];
        mloc[nn * 44 + o] = fmaxf(s, 0.f);
    }
    __syncthreads();
    for (int idx = tid; idx < 32 * D; idx += 256) {
        int o = idx % D, nn = idx / D;
        float s = mb[o];
        #pragma unroll
        for (int i = 0; i < D; i++) s += mloc[nn * 44 + i] * mw_lds[i * D + o];
        out[(size_t)(n0 + nn) * D + o] = fmaxf(s, 0.f);
    }
}

// ---------------- reduce: mean[ph*42+o] += sum_n (out[n,o] + x[n,o]) ------------------------
__global__ void k_reduce(const float* __restrict__ out, const float* __restrict__ su_x,
                         const float* __restrict__ sv_x, float* __restrict__ mean) {
    __shared__ float sdata[6 * D];
    int tid = threadIdx.x;
    int bid = blockIdx.x;
    int n0, ph, nl0;
    const float* x;
    if (bid < NU / 128) { ph = 0; n0 = bid * 128;                 nl0 = n0;      x = su_x; }
    else                { ph = 1; n0 = NU + (bid - NU/128) * 128; nl0 = n0 - NU; x = sv_x; }
    if (tid < 6 * D) {
        int o = tid % D, r = tid / D;
        float acc = 0.f;
        for (int nn = r; nn < 128; nn += 6)
            acc += out[(size_t)(n0 + nn) * D + o] + x[(size_t)(nl0 + nn) * D + o];
        sdata[r * D + o] = acc;
    }
    __syncthreads();
    if (tid < D) {
        float tot = 0.f;
        #pragma unroll
        for (int r = 0; r < 6; r++) tot += sdata[r * D + tid];
        atomicAdd(&mean[ph * D + tid], tot);
    }
}

// ---------------- final MLP --------------------------------------------------------------
__global__ void k_mlp(const float* __restrict__ mean,
                      const float* __restrict__ fc1w, const float* __restrict__ fc1b,
                      const float* __restrict__ fc2w, const float* __restrict__ fc2b,
                      const float* __restrict__ fc3w, const float* __restrict__ fc3b,
                      float* __restrict__ outp) {
    __shared__ float c[4 * D];
    __shared__ float h1[256];
    __shared__ float h2[128];
    int t = threadIdx.x;
    if (t < 4 * D) {
        float v;
        if (t < 2 * D) v = mean[t < D ? t : t - D] * (1.f / NU);
        else { int q = t - 2 * D; v = mean[D + (q < D ? q : q - D)] * (1.f / NV); }
        c[t] = v;
    }
    __syncthreads();
    float s = fc1b[t];
    for (int j = 0; j < 4 * D; j++) s += c[j] * fc1w[j * 256 + t];
    h1[t] = fmaxf(s, 0.f);
    __syncthreads();
    if (t < 128) {
        float s2 = fc2b[t];
        for (int j = 0; j < 256; j++) s2 += h1[j] * fc2w[j * 128 + t];
        h2[t] = fmaxf(s2, 0.f);
    }
    __syncthreads();
    if (t == 0) {
        float s3 = fc3b[0];
        for (int j = 0; j < 128; j++) s3 += h2[j] * fc3w[j];
        outp[0] = s3;
    }
}

extern "C" void kernel_launch(void* const* d_in, const int* in_sizes, int n_in,
                              void* d_out, int out_size, void* d_ws, size_t ws_size,
                              hipStream_t stream) {
    const float* su_x     = (const float*)d_in[0];
    const float* su_e     = (const float*)d_in[1];
    const int*   su_src   = (const int*)d_in[2];
    const int*   su_dst   = (const int*)d_in[3];
    const float* sv_x     = (const float*)d_in[4];
    const float* sv_e     = (const float*)d_in[5];
    const int*   sv_src   = (const int*)d_in[6];
    const int*   sv_dst   = (const int*)d_in[7];
    const float* su_lin0w = (const float*)d_in[8];
    const float* su_lin0b = (const float*)d_in[9];
    const float* su_msgw  = (const float*)d_in[10];
    const float* su_msgb  = (const float*)d_in[11];
    const float* su_en1w  = (const float*)d_in[12];
    const float* su_en1b  = (const float*)d_in[13];
    const float* su_en2w  = (const float*)d_in[14];
    const float* su_en2b  = (const float*)d_in[15];
    const float* su_convb = (const float*)d_in[16];
    const float* sv_lin0w = (const float*)d_in[17];
    const float* sv_lin0b = (const float*)d_in[18];
    const float* sv_msgw  = (const float*)d_in[19];
    const float* sv_msgb  = (const float*)d_in[20];
    const float* sv_en1w  = (const float*)d_in[21];
    const float* sv_en1b  = (const float*)d_in[22];
    const float* sv_en2w  = (const float*)d_in[23];
    const float* sv_en2b  = (const float*)d_in[24];
    const float* sv_convb = (const float*)d_in[25];
    const float* fc1w     = (const float*)d_in[26];
    const float* fc1b     = (const float*)d_in[27];
    const float* fc2w     = (const float*)d_in[28];
    const float* fc2b     = (const float*)d_in[29];
    const float* fc3w     = (const float*)d_in[30];
    const float* fc3b     = (const float*)d_in[31];

    float* ws   = (float*)d_ws;
    float* out  = ws;                            // NT*D
    float* msg0 = out  + (size_t)NT * D;         // ET*D
    float* msg1 = msg0 + (size_t)ET * D;         // ET*D
    float* hs   = msg1 + (size_t)ET * D;         // ET*12
    float* A    = hs   + (size_t)ET * 12;        // 2*D*GP
    float* mean = A    + (size_t)2 * D * GP;     // 128
    int* ib     = (int*)(mean + 128);
    int* outDeg = ib;                            // NT
    int* inDeg  = outDeg + NT;                   // NT
    int* outCnt = inDeg  + NT;                   // NT
    int* inCnt  = outCnt + NT;                   // NT
    int* outOff = inCnt  + NT;                   // NT+1
    int* inOff  = outOff + (NT + 1);             // NT+1
    int* inList = inOff  + (NT + 1);             // ET
    int* srcS   = inList + ET;                   // ET
    int* pOf    = srcS   + ET;                   // ET
    // total ws use ~37 MB

    // zero pred slot + the 16384x20480 interaction output
    hipMemsetAsync(d_out, 0, (size_t)out_size * sizeof(float), stream);

    k_prep<<<(2 * D * GP + 255) / 256, 256, 0, stream>>>(su_en2w, su_en2b, sv_en2w, sv_en2b, A, mean);

    // CSR build
    k_zcnt<<<(4 * NT + 255) / 256, 256, 0, stream>>>(outDeg, 4 * NT);
    k_count<<<(ET + 255) / 256, 256, 0, stream>>>(su_src, su_dst, sv_src, sv_dst, outDeg, inDeg);
    k_scan<<<1, 1024, 0, stream>>>(outDeg, outOff, inDeg, inOff);
    k_place<<<(ET + 255) / 256, 256, 0, stream>>>(su_src, su_dst, sv_src, sv_dst,
                                                  outOff, outCnt, inOff, inCnt, inList, srcS, pOf);
    k_edgeh<<<(ET + 255) / 256, 256, 0, stream>>>(su_e, sv_e, su_en1w, su_en1b, sv_en1w, sv_en1b, pOf, hs);

    float* mbuf[2] = { msg0, msg1 };
    for (int s = 0; s < STEPS; s++) {
        float* mw_ = mbuf[s & 1];                 // write
        float* mr_ = mbuf[(s & 1) ^ 1];           // read (prev step's write)
        if (s == 0) {
            k_step<<<NT / 32, 512, 0, stream>>>(out, A, outOff, srcS, hs, mw_, nullptr,
                                                inOff, inList, su_x, sv_x,
                                                su_lin0w, su_lin0b, sv_lin0w, sv_lin0b,
                                                su_convb, sv_convb, 1);
        } else {
            k_step<<<NT / 32, 512, 0, stream>>>(out, A, outOff, srcS, hs, mw_, mr_,
                                                inOff, inList, su_x, sv_x,
                                                su_msgw, su_msgb, sv_msgw, sv_msgb,
                                                su_convb, sv_convb, 0);
        }
    }
    // final update with msg from step 5 (written to mbuf[(STEPS-1)&1] = mbuf[1])
    k_updF<<<NT / 32, 256, 0, stream>>>(inOff, inList, mbuf[(STEPS - 1) & 1], out,
                                        su_msgw, su_msgb, su_convb, sv_msgw, sv_msgb, sv_convb);

    k_reduce<<<NU / 128 + NV / 128, 256, 0, stream>>>(out, su_x, sv_x, mean);
    k_mlp<<<1, 256, 0, stream>>>(mean, fc1w, fc1b, fc2w, fc2b, fc3w, fc3b, (float*)d_out);
}